// Round 1
// baseline (122.476 us; speedup 1.0000x reference)
//
#include <hip/hip_runtime.h>
#include <math.h>

#define N_G   4096
#define IMW   96
#define IMH   96
#define NPIX  (IMW*IMH)      // 9216
#define NC    16             // gaussian chunks
#define CHUNK (N_G/NC)       // 256
#define FXI   (1.0f/96.0f)
#define FYI   (1.0f/96.0f)
#define NEARP 0.3f
#define EPSV  1e-8f

// ---------------- per-gaussian preprocessing ----------------
__global__ __launch_bounds__(256) void preprocess_k(
    const float* __restrict__ pos, const float* __restrict__ rgb,
    const float* __restrict__ opa, const float* __restrict__ quat,
    const float* __restrict__ scale, const float* __restrict__ rot,
    const float* __restrict__ tran,
    float* __restrict__ key, float* __restrict__ un)
{
    int i = blockIdx.x * blockDim.x + threadIdx.x;
    if (i >= N_G) return;

    float R00=rot[0],R01=rot[1],R02=rot[2];
    float R10=rot[3],R11=rot[4],R12=rot[5];
    float R20=rot[6],R21=rot[7],R22=rot[8];
    float t0=tran[0], t1=tran[1], t2=tran[2];

    float p0 = pos[i*3+0], p1 = pos[i*3+1], p2 = pos[i*3+2];
    float x = R00*p0 + R01*p1 + R02*p2 + t0;
    float y = R10*p0 + R11*p1 + R12*p2 + t1;
    float z = R20*p0 + R21*p1 + R22*p2 + t2;
    float r = sqrtf(x*x + y*y + z*z);
    float invz = 1.0f / z;
    float mu = x * invz, mv = y * invz;

    // J (rows: [1/z,0,-x/z^2],[0,1/z,-y/z^2],[x/r,y/r,z/r])
    float J00 = invz,  J02 = -x*invz*invz;
    float J11 = invz,  J12 = -y*invz*invz;
    // JW = J @ rot (rows 0,1 only needed for cov2d)
    float JW00 = J00*R00 + J02*R20;
    float JW01 = J00*R01 + J02*R21;
    float JW02 = J00*R02 + J02*R22;
    float JW10 = J11*R10 + J12*R20;
    float JW11 = J11*R11 + J12*R21;
    float JW12 = J11*R12 + J12*R22;

    // quaternion -> rotation
    float qw = quat[i*4+0], qx = quat[i*4+1], qy = quat[i*4+2], qz = quat[i*4+3];
    float qn = sqrtf(qw*qw+qx*qx+qy*qy+qz*qz) + 1e-12f;
    float qi = 1.0f/qn;
    qw*=qi; qx*=qi; qy*=qi; qz*=qi;
    float Q00 = 1.f-2.f*(qy*qy+qz*qz), Q01 = 2.f*(qx*qy - qw*qz), Q02 = 2.f*(qx*qz + qw*qy);
    float Q10 = 2.f*(qx*qy + qw*qz), Q11 = 1.f-2.f*(qx*qx+qz*qz), Q12 = 2.f*(qy*qz - qw*qx);
    float Q20 = 2.f*(qx*qz - qw*qy), Q21 = 2.f*(qy*qz + qw*qx), Q22 = 1.f-2.f*(qx*qx+qy*qy);

    float s0 = fabsf(scale[i*3+0]) + 1e-4f;
    float s1 = fabsf(scale[i*3+1]) + 1e-4f;
    float s2 = fabsf(scale[i*3+2]) + 1e-4f;
    float A00=Q00*s0, A01=Q01*s1, A02=Q02*s2;
    float A10=Q10*s0, A11=Q11*s1, A12=Q12*s2;
    float A20=Q20*s0, A21=Q21*s1, A22=Q22*s2;
    // cov3d = A A^T
    float C00 = A00*A00+A01*A01+A02*A02;
    float C01 = A00*A10+A01*A11+A02*A12;
    float C02 = A00*A20+A01*A21+A02*A22;
    float C11 = A10*A10+A11*A11+A12*A12;
    float C12 = A10*A20+A11*A21+A12*A22;
    float C22 = A20*A20+A21*A21+A22*A22;
    // cov2d = JW cov3d JW^T (2x2)
    float M00 = JW00*C00 + JW01*C01 + JW02*C02;
    float M01 = JW00*C01 + JW01*C11 + JW02*C12;
    float M02 = JW00*C02 + JW01*C12 + JW02*C22;
    float M10 = JW10*C00 + JW11*C01 + JW12*C02;
    float M11 = JW10*C01 + JW11*C11 + JW12*C12;
    float M12 = JW10*C02 + JW11*C12 + JW12*C22;
    float a = M00*JW00 + M01*JW01 + M02*JW02 + EPSV;
    float d = M10*JW10 + M11*JW11 + M12*JW12 + EPSV;
    float b = 0.5f*((M00*JW10 + M01*JW11 + M02*JW12) +
                    (M10*JW00 + M11*JW01 + M12*JW02));
    float invdet = 1.0f/(a*d - b*b);
    // premultiplied quadratic coeffs: power = iaP*dx^2 + ibP*dx*dy + idP*dy^2
    float iaP = -0.5f * d * invdet;
    float ibP =  b * invdet;          // -0.5 * 2 * (-b/det)
    float idP = -0.5f * a * invdet;

    float sig_o = 1.0f/(1.0f + __expf(-opa[i]));
    float valid = (z > NEARP) ? 1.0f : 0.0f;

    key[i] = r;
    un[0*N_G+i] = mu;
    un[1*N_G+i] = mv;
    un[2*N_G+i] = iaP;
    un[3*N_G+i] = ibP;
    un[4*N_G+i] = idP;
    un[5*N_G+i] = sig_o * valid;
    un[6*N_G+i] = 1.0f/(1.0f+__expf(-rgb[i*3+0]));
    un[7*N_G+i] = 1.0f/(1.0f+__expf(-rgb[i*3+1]));
    un[8*N_G+i] = 1.0f/(1.0f+__expf(-rgb[i*3+2]));
}

// ---------------- single-block bitonic argsort (ascending by key) ----------------
__global__ __launch_bounds__(1024) void sort_k(const float* __restrict__ key,
                                               int* __restrict__ order)
{
    __shared__ float sk[N_G];
    __shared__ int   sv[N_G];
    int t = threadIdx.x;
    for (int i = t; i < N_G; i += 1024) { sk[i] = key[i]; sv[i] = i; }
    __syncthreads();
    for (int k = 2; k <= N_G; k <<= 1) {
        for (int j = k >> 1; j > 0; j >>= 1) {
            for (int i = t; i < N_G; i += 1024) {
                int ixj = i ^ j;
                if (ixj > i) {
                    bool up = ((i & k) == 0);
                    float ki = sk[i], kj = sk[ixj];
                    bool sw = up ? (ki > kj) : (ki < kj);
                    if (sw) {
                        sk[i] = kj; sk[ixj] = ki;
                        int v = sv[i]; sv[i] = sv[ixj]; sv[ixj] = v;
                    }
                }
            }
            __syncthreads();
        }
    }
    for (int i = t; i < N_G; i += 1024) order[i] = sv[i];
}

// ---------------- gather into sorted SoA ----------------
__global__ __launch_bounds__(256) void gather_k(const int* __restrict__ order,
                                                const float* __restrict__ un,
                                                float* __restrict__ so)
{
    int i = blockIdx.x * blockDim.x + threadIdx.x;
    if (i >= N_G) return;
    int o = order[i];
    #pragma unroll
    for (int a = 0; a < 9; a++) so[a*N_G + i] = un[a*N_G + o];
}

// ---------------- chunked composite partials ----------------
__global__ __launch_bounds__(256) void partial_k(const float* __restrict__ so,
                                                 float* __restrict__ partials)
{
    __shared__ float sh[9][CHUNK];
    int t = threadIdx.x;
    int chunk = blockIdx.y;
    int gbase = chunk * CHUNK;
    #pragma unroll
    for (int a = 0; a < 9; a++) sh[a][t] = so[a*N_G + gbase + t];
    __syncthreads();

    int pixel = blockIdx.x * 256 + t;
    int px = pixel % IMW, py = pixel / IMW;
    float pu = ((float)px + 0.5f - IMW*0.5f) * FXI;
    float pv = ((float)py + 0.5f - IMH*0.5f) * FYI;

    float T = 1.0f, cr = 0.0f, cg = 0.0f, cb = 0.0f;
    #pragma unroll 4
    for (int g = 0; g < CHUNK; g++) {
        float dx = pu - sh[0][g];
        float dy = pv - sh[1][g];
        float pw = sh[2][g]*dx*dx + sh[3][g]*dx*dy + sh[4][g]*dy*dy;
        float al = fminf(sh[5][g] * __expf(pw), 0.99f);
        float w = T * al;
        cr += w * sh[6][g];
        cg += w * sh[7][g];
        cb += w * sh[8][g];
        T *= (1.0f - al);
    }
    float4* out4 = (float4*)partials;
    out4[pixel*NC + chunk] = make_float4(cr, cg, cb, T);
}

// ---------------- per-pixel chunk combine ----------------
__global__ __launch_bounds__(256) void combine_k(const float* __restrict__ partials,
                                                 float* __restrict__ out)
{
    int p = blockIdx.x * blockDim.x + threadIdx.x;
    if (p >= NPIX) return;
    const float4* pp = (const float4*)partials + p*NC;
    float T = 1.0f, r = 0.0f, g = 0.0f, b = 0.0f;
    #pragma unroll
    for (int c = 0; c < NC; c++) {
        float4 v = pp[c];
        r += T * v.x; g += T * v.y; b += T * v.z;
        T *= v.w;
    }
    out[p*3+0] = r; out[p*3+1] = g; out[p*3+2] = b;
}

extern "C" void kernel_launch(void* const* d_in, const int* in_sizes, int n_in,
                              void* d_out, int out_size, void* d_ws, size_t ws_size,
                              hipStream_t stream) {
    const float* pos   = (const float*)d_in[0];
    const float* rgb   = (const float*)d_in[1];
    const float* opa   = (const float*)d_in[2];
    const float* quat  = (const float*)d_in[3];
    const float* scale = (const float*)d_in[4];
    const float* rot   = (const float*)d_in[5];
    const float* tran  = (const float*)d_in[6];
    float* out = (float*)d_out;

    float* ws       = (float*)d_ws;
    float* key      = ws;                 // N_G
    int*   order    = (int*)(ws + N_G);   // N_G
    float* un       = ws + 2*N_G;         // 9*N_G
    float* so       = ws + 11*N_G;        // 9*N_G
    float* partials = ws + 20*N_G;        // NPIX*NC*4

    preprocess_k<<<N_G/256, 256, 0, stream>>>(pos, rgb, opa, quat, scale, rot, tran, key, un);
    sort_k<<<1, 1024, 0, stream>>>(key, order);
    gather_k<<<N_G/256, 256, 0, stream>>>(order, un, so);
    partial_k<<<dim3(NPIX/256, NC), 256, 0, stream>>>(so, partials);
    combine_k<<<(NPIX+255)/256, 256, 0, stream>>>(partials, out);
}

// Round 2
// 48.922 us; speedup vs baseline: 2.5035x; 2.5035x over previous
//
#include <hip/hip_runtime.h>
#include <math.h>

#define N_G   4096
#define IMW   96
#define IMH   96
#define NPIX  (IMW*IMH)      // 9216
#define NC    16             // gaussian chunks for composite partials
#define CHUNK (N_G/NC)       // 256
#define FXI   (1.0f/96.0f)
#define FYI   (1.0f/96.0f)
#define NEARP 0.3f
#define EPSV  1e-8f
#define LOG2E 1.4426950408889634f

// ---------------- per-gaussian preprocessing (AoS 3x float4 per gaussian) ----
// slot0: {mu, mv, iaP, ibP}  slot1: {idP, opa_eff, cr, cg}  slot2: {cb,0,0,0}
// quadratic coeffs premultiplied by log2(e) so composite uses exp2 directly.
__global__ __launch_bounds__(256) void preprocess_k(
    const float* __restrict__ pos, const float* __restrict__ rgb,
    const float* __restrict__ opa, const float* __restrict__ quat,
    const float* __restrict__ scale, const float* __restrict__ rot,
    const float* __restrict__ tran,
    float* __restrict__ key, int* __restrict__ rank, float4* __restrict__ un4)
{
    int i = blockIdx.x * blockDim.x + threadIdx.x;
    if (i >= N_G) return;

    float R00=rot[0],R01=rot[1],R02=rot[2];
    float R10=rot[3],R11=rot[4],R12=rot[5];
    float R20=rot[6],R21=rot[7],R22=rot[8];
    float t0=tran[0], t1=tran[1], t2=tran[2];

    float p0 = pos[i*3+0], p1 = pos[i*3+1], p2 = pos[i*3+2];
    float x = R00*p0 + R01*p1 + R02*p2 + t0;
    float y = R10*p0 + R11*p1 + R12*p2 + t1;
    float z = R20*p0 + R21*p1 + R22*p2 + t2;
    float rr = sqrtf(x*x + y*y + z*z);
    float invz = 1.0f / z;
    float mu = x * invz, mv = y * invz;

    float J00 = invz,  J02 = -x*invz*invz;
    float J11 = invz,  J12 = -y*invz*invz;
    float JW00 = J00*R00 + J02*R20;
    float JW01 = J00*R01 + J02*R21;
    float JW02 = J00*R02 + J02*R22;
    float JW10 = J11*R10 + J12*R20;
    float JW11 = J11*R11 + J12*R21;
    float JW12 = J11*R12 + J12*R22;

    float qw = quat[i*4+0], qx = quat[i*4+1], qy = quat[i*4+2], qz = quat[i*4+3];
    float qn = sqrtf(qw*qw+qx*qx+qy*qy+qz*qz) + 1e-12f;
    float qi = 1.0f/qn;
    qw*=qi; qx*=qi; qy*=qi; qz*=qi;
    float Q00 = 1.f-2.f*(qy*qy+qz*qz), Q01 = 2.f*(qx*qy - qw*qz), Q02 = 2.f*(qx*qz + qw*qy);
    float Q10 = 2.f*(qx*qy + qw*qz), Q11 = 1.f-2.f*(qx*qx+qz*qz), Q12 = 2.f*(qy*qz - qw*qx);
    float Q20 = 2.f*(qx*qz - qw*qy), Q21 = 2.f*(qy*qz + qw*qx), Q22 = 1.f-2.f*(qx*qx+qy*qy);

    float s0 = fabsf(scale[i*3+0]) + 1e-4f;
    float s1 = fabsf(scale[i*3+1]) + 1e-4f;
    float s2 = fabsf(scale[i*3+2]) + 1e-4f;
    float A00=Q00*s0, A01=Q01*s1, A02=Q02*s2;
    float A10=Q10*s0, A11=Q11*s1, A12=Q12*s2;
    float A20=Q20*s0, A21=Q21*s1, A22=Q22*s2;
    float C00 = A00*A00+A01*A01+A02*A02;
    float C01 = A00*A10+A01*A11+A02*A12;
    float C02 = A00*A20+A01*A21+A02*A22;
    float C11 = A10*A10+A11*A11+A12*A12;
    float C12 = A10*A20+A11*A21+A12*A22;
    float C22 = A20*A20+A21*A21+A22*A22;
    float M00 = JW00*C00 + JW01*C01 + JW02*C02;
    float M01 = JW00*C01 + JW01*C11 + JW02*C12;
    float M02 = JW00*C02 + JW01*C12 + JW02*C22;
    float M10 = JW10*C00 + JW11*C01 + JW12*C02;
    float M11 = JW10*C01 + JW11*C11 + JW12*C12;
    float M12 = JW10*C02 + JW11*C12 + JW12*C22;
    float a = M00*JW00 + M01*JW01 + M02*JW02 + EPSV;
    float d = M10*JW10 + M11*JW11 + M12*JW12 + EPSV;
    float b = 0.5f*((M00*JW10 + M01*JW11 + M02*JW12) +
                    (M10*JW00 + M11*JW01 + M12*JW02));
    float invdet = 1.0f/(a*d - b*b);
    float iaP = -0.5f * d * invdet * LOG2E;
    float ibP =  b * invdet * LOG2E;
    float idP = -0.5f * a * invdet * LOG2E;

    float sig_o = 1.0f/(1.0f + __expf(-opa[i]));
    float valid = (z > NEARP) ? 1.0f : 0.0f;
    float c0 = 1.0f/(1.0f+__expf(-rgb[i*3+0]));
    float c1 = 1.0f/(1.0f+__expf(-rgb[i*3+1]));
    float c2 = 1.0f/(1.0f+__expf(-rgb[i*3+2]));

    key[i]  = rr;
    rank[i] = 0;
    un4[i*3+0] = make_float4(mu, mv, iaP, ibP);
    un4[i*3+1] = make_float4(idP, sig_o*valid, c0, c1);
    un4[i*3+2] = make_float4(c2, 0.0f, 0.0f, 0.0f);
}

// ---------------- rank by counting (stable argsort equivalent) --------------
// rank[i] = #{j : pk_j < pk_i} with pk = (float_bits(key)<<32)|idx (keys > 0).
__global__ __launch_bounds__(256) void rank_k(const float* __restrict__ key,
                                              int* __restrict__ rank)
{
    __shared__ unsigned long long sk[256];
    int t = threadIdx.x;
    int gi = blockIdx.x * 256 + t;      // gaussian handled by this thread
    int kj = blockIdx.y * 256 + t;      // key staged by this thread
    sk[t] = ((unsigned long long)__float_as_uint(key[kj]) << 32) | (unsigned int)kj;
    __syncthreads();
    unsigned long long pk =
        ((unsigned long long)__float_as_uint(key[gi]) << 32) | (unsigned int)gi;
    int cnt = 0;
    #pragma unroll 8
    for (int j = 0; j < 256; j++) cnt += (sk[j] < pk) ? 1 : 0;
    atomicAdd(&rank[gi], cnt);
}

// ---------------- scatter into sorted AoS -----------------------------------
__global__ __launch_bounds__(256) void scatter_k(const int* __restrict__ rank,
                                                 const float4* __restrict__ un4,
                                                 float4* __restrict__ so4)
{
    int i = blockIdx.x * 256 + threadIdx.x;
    int r = rank[i];
    so4[r*3+0] = un4[i*3+0];
    so4[r*3+1] = un4[i*3+1];
    so4[r*3+2] = un4[i*3+2];
}

// ---------------- chunked composite partials --------------------------------
__global__ __launch_bounds__(256) void partial_k(const float4* __restrict__ so4,
                                                 float4* __restrict__ partials)
{
    __shared__ float4 sh[CHUNK*3];
    int t = threadIdx.x;
    int chunk = blockIdx.y;
    int gbase = chunk * CHUNK;
    #pragma unroll
    for (int k = 0; k < 3; k++) sh[t*3+k] = so4[(gbase+t)*3+k];
    __syncthreads();

    int pixel = blockIdx.x * 256 + t;
    int px = pixel % IMW, py = pixel / IMW;
    float pu = ((float)px + 0.5f - IMW*0.5f) * FXI;
    float pv = ((float)py + 0.5f - IMH*0.5f) * FYI;

    float T = 1.0f, cr = 0.0f, cg = 0.0f, cb = 0.0f;
    #pragma unroll 4
    for (int g = 0; g < CHUNK; g++) {
        float4 v0 = sh[g*3+0];
        float4 v1 = sh[g*3+1];
        float4 v2 = sh[g*3+2];
        float dx = pu - v0.x;
        float dy = pv - v0.y;
        float pw = dx*(v0.z*dx + v0.w*dy) + v1.x*dy*dy;   // log2-scaled power
        float al = fminf(v1.y * __builtin_amdgcn_exp2f(pw), 0.99f);
        float w = T * al;
        cr += w * v1.z;
        cg += w * v1.w;
        cb += w * v2.x;
        T *= (1.0f - al);
    }
    partials[pixel*NC + chunk] = make_float4(cr, cg, cb, T);
}

// ---------------- per-pixel chunk combine -----------------------------------
__global__ __launch_bounds__(256) void combine_k(const float4* __restrict__ partials,
                                                 float* __restrict__ out)
{
    int p = blockIdx.x * blockDim.x + threadIdx.x;
    if (p >= NPIX) return;
    const float4* pp = partials + p*NC;
    float T = 1.0f, r = 0.0f, g = 0.0f, b = 0.0f;
    #pragma unroll
    for (int c = 0; c < NC; c++) {
        float4 v = pp[c];
        r += T * v.x; g += T * v.y; b += T * v.z;
        T *= v.w;
    }
    out[p*3+0] = r; out[p*3+1] = g; out[p*3+2] = b;
}

extern "C" void kernel_launch(void* const* d_in, const int* in_sizes, int n_in,
                              void* d_out, int out_size, void* d_ws, size_t ws_size,
                              hipStream_t stream) {
    const float* pos   = (const float*)d_in[0];
    const float* rgb   = (const float*)d_in[1];
    const float* opa   = (const float*)d_in[2];
    const float* quat  = (const float*)d_in[3];
    const float* scale = (const float*)d_in[4];
    const float* rot   = (const float*)d_in[5];
    const float* tran  = (const float*)d_in[6];
    float* out = (float*)d_out;

    float* ws        = (float*)d_ws;
    float*  key      = ws;                      // 4096
    int*    rank     = (int*)(ws + N_G);        // 4096
    float4* un4      = (float4*)(ws + 2*N_G);   // 4096*3 float4 = 49152 f
    float4* so4      = un4 + N_G*3;             // 49152 f
    float4* partials = so4 + N_G*3;             // 9216*16 float4 = 589824 f

    preprocess_k<<<N_G/256, 256, 0, stream>>>(pos, rgb, opa, quat, scale, rot, tran,
                                              key, rank, un4);
    rank_k<<<dim3(N_G/256, N_G/256), 256, 0, stream>>>(key, rank);
    scatter_k<<<N_G/256, 256, 0, stream>>>(rank, un4, so4);
    partial_k<<<dim3(NPIX/256, NC), 256, 0, stream>>>(so4, partials);
    combine_k<<<(NPIX+255)/256, 256, 0, stream>>>(partials, out);
}

// Round 3
// 30.181 us; speedup vs baseline: 4.0581x; 1.6210x over previous
//
#include <hip/hip_runtime.h>
#include <math.h>

#define N_G   4096
#define IMW   96
#define IMH   96
#define NPIX  (IMW*IMH)      // 9216
#define NC    32             // gaussian chunks for composite partials
#define CHUNK (N_G/NC)       // 128
#define TILES_X 6
#define TILES_Y 6
#define NTILE (TILES_X*TILES_Y)   // 36 tiles of 16x16 px
#define FXI   (1.0f/96.0f)
#define FYI   (1.0f/96.0f)
#define NEARP 0.3f
#define EPSV  1e-8f
#define LOG2E 1.4426950408889634f

// ---------------- per-gaussian preprocessing ---------------------------------
// un4 slot0: {mu, mv, iaP, ibP}  slot1: {idP, opa_eff, cr, cg}  slot2: {cb,0,0,0}
// ucull:     {mu, mv, cull_r2, 0}   cull_r2 in uv^2 units (conservative)
// quadratic coeffs premultiplied by log2(e) so composite uses exp2 directly.
__global__ __launch_bounds__(256) void preprocess_k(
    const float* __restrict__ pos, const float* __restrict__ rgb,
    const float* __restrict__ opa, const float* __restrict__ quat,
    const float* __restrict__ scale, const float* __restrict__ rot,
    const float* __restrict__ tran,
    float* __restrict__ key, int* __restrict__ rank,
    float4* __restrict__ un4, float4* __restrict__ ucull)
{
    int i = blockIdx.x * blockDim.x + threadIdx.x;
    if (i >= N_G) return;

    float R00=rot[0],R01=rot[1],R02=rot[2];
    float R10=rot[3],R11=rot[4],R12=rot[5];
    float R20=rot[6],R21=rot[7],R22=rot[8];
    float t0=tran[0], t1=tran[1], t2=tran[2];

    float p0 = pos[i*3+0], p1 = pos[i*3+1], p2 = pos[i*3+2];
    float x = R00*p0 + R01*p1 + R02*p2 + t0;
    float y = R10*p0 + R11*p1 + R12*p2 + t1;
    float z = R20*p0 + R21*p1 + R22*p2 + t2;
    float rr = sqrtf(x*x + y*y + z*z);
    float invz = 1.0f / z;
    float mu = x * invz, mv = y * invz;

    float J00 = invz,  J02 = -x*invz*invz;
    float J11 = invz,  J12 = -y*invz*invz;
    float JW00 = J00*R00 + J02*R20;
    float JW01 = J00*R01 + J02*R21;
    float JW02 = J00*R02 + J02*R22;
    float JW10 = J11*R10 + J12*R20;
    float JW11 = J11*R11 + J12*R21;
    float JW12 = J11*R12 + J12*R22;

    float qw = quat[i*4+0], qx = quat[i*4+1], qy = quat[i*4+2], qz = quat[i*4+3];
    float qn = sqrtf(qw*qw+qx*qx+qy*qy+qz*qz) + 1e-12f;
    float qi = 1.0f/qn;
    qw*=qi; qx*=qi; qy*=qi; qz*=qi;
    float Q00 = 1.f-2.f*(qy*qy+qz*qz), Q01 = 2.f*(qx*qy - qw*qz), Q02 = 2.f*(qx*qz + qw*qy);
    float Q10 = 2.f*(qx*qy + qw*qz), Q11 = 1.f-2.f*(qx*qx+qz*qz), Q12 = 2.f*(qy*qz - qw*qx);
    float Q20 = 2.f*(qx*qz - qw*qy), Q21 = 2.f*(qy*qz + qw*qx), Q22 = 1.f-2.f*(qx*qx+qy*qy);

    float s0 = fabsf(scale[i*3+0]) + 1e-4f;
    float s1 = fabsf(scale[i*3+1]) + 1e-4f;
    float s2 = fabsf(scale[i*3+2]) + 1e-4f;
    float A00=Q00*s0, A01=Q01*s1, A02=Q02*s2;
    float A10=Q10*s0, A11=Q11*s1, A12=Q12*s2;
    float A20=Q20*s0, A21=Q21*s1, A22=Q22*s2;
    float C00 = A00*A00+A01*A01+A02*A02;
    float C01 = A00*A10+A01*A11+A02*A12;
    float C02 = A00*A20+A01*A21+A02*A22;
    float C11 = A10*A10+A11*A11+A12*A12;
    float C12 = A10*A20+A11*A21+A12*A22;
    float C22 = A20*A20+A21*A21+A22*A22;
    float M00 = JW00*C00 + JW01*C01 + JW02*C02;
    float M01 = JW00*C01 + JW01*C11 + JW02*C12;
    float M02 = JW00*C02 + JW01*C12 + JW02*C22;
    float M10 = JW10*C00 + JW11*C01 + JW12*C02;
    float M11 = JW10*C01 + JW11*C11 + JW12*C12;
    float M12 = JW10*C02 + JW11*C12 + JW12*C22;
    float a = M00*JW00 + M01*JW01 + M02*JW02 + EPSV;
    float d = M10*JW10 + M11*JW11 + M12*JW12 + EPSV;
    float b = 0.5f*((M00*JW10 + M01*JW11 + M02*JW12) +
                    (M10*JW00 + M11*JW01 + M12*JW02));
    float invdet = 1.0f/(a*d - b*b);
    float iaP = -0.5f * d * invdet * LOG2E;
    float ibP =  b * invdet * LOG2E;
    float idP = -0.5f * a * invdet * LOG2E;

    float sig_o = 1.0f/(1.0f + __expf(-opa[i]));
    float valid = (z > NEARP) ? 1.0f : 0.0f;
    float c0 = 1.0f/(1.0f+__expf(-rgb[i*3+0]));
    float c1 = 1.0f/(1.0f+__expf(-rgb[i*3+1]));
    float c2 = 1.0f/(1.0f+__expf(-rgb[i*3+2]));
    float opa_eff = sig_o * valid;

    // conservative cull radius^2: power(d) = -d^T Q d (log2 units), Q PD.
    // power_max over rect <= -lam_min(Q)*dist^2. Drop if alpha < opa*2^-34.
    float q00 = -iaP, q01 = -0.5f*ibP, q11 = -idP;
    float df = q00 - q11;
    float lam = 0.5f*((q00 + q11) - sqrtf(df*df + 4.0f*q01*q01));
    lam = fmaxf(lam, 1e-20f);
    float cull_r2 = (34.0f + log2f(opa_eff)) / lam;   // -inf when opa_eff==0

    key[i]  = rr;
    rank[i] = 0;
    un4[i*3+0] = make_float4(mu, mv, iaP, ibP);
    un4[i*3+1] = make_float4(idP, opa_eff, c0, c1);
    un4[i*3+2] = make_float4(c2, 0.0f, 0.0f, 0.0f);
    ucull[i]   = make_float4(mu, mv, cull_r2, 0.0f);
}

// ---------------- rank by counting (stable argsort equivalent) --------------
// rank[i] = #{j : pk_j < pk_i} with pk = (float_bits(key)<<32)|idx (keys > 0).
__global__ __launch_bounds__(256) void rank_k(const float* __restrict__ key,
                                              int* __restrict__ rank)
{
    __shared__ unsigned long long sk[256];
    int t = threadIdx.x;
    int gi = blockIdx.x * 256 + t;      // gaussian handled by this thread
    int kj = blockIdx.y * 256 + t;      // key staged by this thread
    sk[t] = ((unsigned long long)__float_as_uint(key[kj]) << 32) | (unsigned int)kj;
    __syncthreads();
    unsigned long long pk =
        ((unsigned long long)__float_as_uint(key[gi]) << 32) | (unsigned int)gi;
    int cnt = 0;
    #pragma unroll 8
    for (int j = 0; j < 256; j++) cnt += (sk[j] < pk) ? 1 : 0;
    atomicAdd(&rank[gi], cnt);
}

// ---------------- scatter into sorted AoS -----------------------------------
__global__ __launch_bounds__(256) void scatter_k(const int* __restrict__ rank,
                                                 const float4* __restrict__ un4,
                                                 const float4* __restrict__ ucull,
                                                 float4* __restrict__ so4,
                                                 float4* __restrict__ scull)
{
    int i = blockIdx.x * 256 + threadIdx.x;
    int r = rank[i];
    so4[r*3+0] = un4[i*3+0];
    so4[r*3+1] = un4[i*3+1];
    so4[r*3+2] = un4[i*3+2];
    scull[r]   = ucull[i];
}

// ---------------- cull + compact + composite partials -----------------------
// block = (tile of 16x16 px, chunk of 128 sorted gaussians)
__global__ __launch_bounds__(256) void partial_k(const float4* __restrict__ so4,
                                                 const float4* __restrict__ scull,
                                                 float4* __restrict__ partials)
{
    __shared__ float4 g0[CHUNK], g1[CHUNK], g2[CHUNK];
    __shared__ int wsum[4];
    int t = threadIdx.x;
    int tile = blockIdx.x;
    int chunk = blockIdx.y;
    int tx = tile % TILES_X, ty = tile / TILES_X;
    float u0 = ((float)(tx*16) + 0.5f - 48.0f) * FXI;
    float u1 = u0 + 15.0f * FXI;
    float v0 = ((float)(ty*16) + 0.5f - 48.0f) * FYI;
    float v1 = v0 + 15.0f * FYI;

    // cull test: one gaussian per thread (threads >= CHUNK idle)
    bool flag = false;
    int gi = chunk*CHUNK + t;
    if (t < CHUNK) {
        float4 cq = scull[gi];
        float cu = fminf(fmaxf(cq.x, u0), u1);
        float cv = fminf(fmaxf(cq.y, v0), v1);
        float ddx = cq.x - cu, ddy = cq.y - cv;
        flag = (ddx*ddx + ddy*ddy) <= cq.z;   // false for NaN/-inf r2
    }
    unsigned long long m = __ballot(flag);
    int wid = t >> 6, lane = t & 63;
    if (lane == 0) wsum[wid] = __popcll(m);
    __syncthreads();
    int total = wsum[0] + wsum[1] + wsum[2] + wsum[3];
    if (flag) {
        int base = 0;
        #pragma unroll
        for (int w = 0; w < 3; w++) base += (w < wid) ? wsum[w] : 0;
        int pos = base + __popcll(m & ((1ull << lane) - 1ull));
        g0[pos] = so4[gi*3+0];
        g1[pos] = so4[gi*3+1];
        g2[pos] = so4[gi*3+2];
    }
    __syncthreads();

    int px = tx*16 + (t & 15);
    int py = ty*16 + (t >> 4);
    int pixel = py * IMW + px;
    float pu = ((float)px + 0.5f - 48.0f) * FXI;
    float pv = ((float)py + 0.5f - 48.0f) * FYI;

    float T = 1.0f, cr = 0.0f, cg = 0.0f, cb = 0.0f;
    #pragma unroll 2
    for (int g = 0; g < total; g++) {
        float4 a0 = g0[g];
        float4 a1 = g1[g];
        float4 a2 = g2[g];
        float dx = pu - a0.x;
        float dy = pv - a0.y;
        float pw = dx*(a0.z*dx + a0.w*dy) + a1.x*dy*dy;   // log2-scaled power
        float al = fminf(a1.y * __builtin_amdgcn_exp2f(pw), 0.99f);
        float w = T * al;
        cr += w * a1.z;
        cg += w * a1.w;
        cb += w * a2.x;
        T *= (1.0f - al);
    }
    partials[pixel*NC + chunk] = make_float4(cr, cg, cb, T);
}

// ---------------- per-pixel chunk combine -----------------------------------
__global__ __launch_bounds__(256) void combine_k(const float4* __restrict__ partials,
                                                 float* __restrict__ out)
{
    int p = blockIdx.x * blockDim.x + threadIdx.x;
    if (p >= NPIX) return;
    const float4* pp = partials + p*NC;
    float T = 1.0f, r = 0.0f, g = 0.0f, b = 0.0f;
    #pragma unroll
    for (int c = 0; c < NC; c++) {
        float4 v = pp[c];
        r += T * v.x; g += T * v.y; b += T * v.z;
        T *= v.w;
    }
    out[p*3+0] = r; out[p*3+1] = g; out[p*3+2] = b;
}

extern "C" void kernel_launch(void* const* d_in, const int* in_sizes, int n_in,
                              void* d_out, int out_size, void* d_ws, size_t ws_size,
                              hipStream_t stream) {
    const float* pos   = (const float*)d_in[0];
    const float* rgb   = (const float*)d_in[1];
    const float* opa   = (const float*)d_in[2];
    const float* quat  = (const float*)d_in[3];
    const float* scale = (const float*)d_in[4];
    const float* rot   = (const float*)d_in[5];
    const float* tran  = (const float*)d_in[6];
    float* out = (float*)d_out;

    float* ws        = (float*)d_ws;
    float*  key      = ws;                      // 4096 f
    int*    rank     = (int*)(ws + N_G);        // 4096 i
    float4* un4      = (float4*)(ws + 2*N_G);   // 4096*3 f4
    float4* ucull    = un4 + N_G*3;             // 4096 f4
    float4* so4      = ucull + N_G;             // 4096*3 f4
    float4* scull    = so4 + N_G*3;             // 4096 f4
    float4* partials = scull + N_G;             // 9216*32 f4 (~4.7 MB)

    preprocess_k<<<N_G/256, 256, 0, stream>>>(pos, rgb, opa, quat, scale, rot, tran,
                                              key, rank, un4, ucull);
    rank_k<<<dim3(N_G/256, N_G/256), 256, 0, stream>>>(key, rank);
    scatter_k<<<N_G/256, 256, 0, stream>>>(rank, un4, ucull, so4, scull);
    partial_k<<<dim3(NTILE, NC), 256, 0, stream>>>(so4, scull, partials);
    combine_k<<<(NPIX+255)/256, 256, 0, stream>>>(partials, out);
}